// Round 13
// baseline (206.737 us; speedup 1.0000x reference)
//
#include <hip/hip_runtime.h>
#include <stdint.h>

#define LL 1024
#define NB 8
#define EE 1024
#define HH 16
#define DD 64
#define MM (LL*NB)      // 8192 rows (l*NB+n)
#define K3 (3*EE)       // 3072

typedef __attribute__((ext_vector_type(8))) short bf16x8;   // 8 bf16 in 4 VGPRs
typedef __attribute__((ext_vector_type(4))) float f32x4;
typedef __attribute__((ext_vector_type(4))) unsigned short u16x4;
typedef __attribute__((ext_vector_type(8))) unsigned short u16x8;

__device__ __forceinline__ unsigned short f2bf(float f) {
  uint32_t u = __builtin_bit_cast(uint32_t, f);
  u += 0x7fffu + ((u >> 16) & 1u);           // RNE
  return (unsigned short)(u >> 16);
}
// HW RNE pack: dst = [bf16(hi)|bf16(lo)] — bit-identical to f2bf pairs
__device__ __forceinline__ uint32_t cvtpk(float lo, float hi) {
  uint32_t d;
  asm volatile("v_cvt_pk_bf16_f32 %0, %1, %2" : "=v"(d) : "v"(lo), "v"(hi));
  return d;
}
__device__ __forceinline__ f32x4 mfma16(bf16x8 a, bf16x8 b, f32x4 c) {
  return __builtin_amdgcn_mfma_f32_16x16x32_bf16(a, b, c, 0, 0, 0);
}
__device__ __forceinline__ void gload16(const unsigned short* src, unsigned short* dst) {
  __builtin_amdgcn_global_load_lds(
      (const __attribute__((address_space(1))) uint32_t*)src,
      (__attribute__((address_space(3))) uint32_t*)dst, 16, 0, 0);
}

// ---------------- fp32 -> bf16 convert (all three inputs, one launch) ----------------
__global__ void cvt3_kernel(const float* __restrict__ a, const float* __restrict__ b,
                            const float* __restrict__ c,
                            unsigned short* __restrict__ da, unsigned short* __restrict__ db,
                            unsigned short* __restrict__ dc) {
  const int NA = (MM * EE) / 4, NBq = (K3 * EE) / 4, NC = (EE * EE) / 4;
  const int total = NA + NBq + NC;
  for (int i = blockIdx.x * blockDim.x + threadIdx.x; i < total; i += gridDim.x * blockDim.x) {
    const float* s; unsigned short* d; int j;
    if (i < NA)            { s = a; d = da; j = i; }
    else if (i < NA + NBq) { s = b; d = db; j = i - NA; }
    else                   { s = c; d = dc; j = i - NA - NBq; }
    f32x4 v = ((const f32x4*)s)[j];
    u16x4 o;
    o[0] = f2bf(v[0]); o[1] = f2bf(v[1]); o[2] = f2bf(v[2]); o[3] = f2bf(v[3]);
    ((u16x4*)d)[j] = o;
  }
}

// ---------------- in-proj GEMM (round-10 proven, 82 us): 128x128 tile ----------------
// C[m][c] = sum_k A[m][k]*W[c][k] + bias[c]; bf16 out via LDS-coalesced epilogue:
//   c in [0,1024)    -> qo[m][c] * 0.125 (exact)
//   c in [1024,2048) -> kto[n][h][l][d]
//   c in [2048,3072) -> vo[m][c-2048]
// Double-buffered 32KB LDS, 1 barrier/K-step, stage issued right after it.
__global__ __launch_bounds__(256) void gemm_in(
    const unsigned short* __restrict__ A, const unsigned short* __restrict__ B,
    const float* __restrict__ bias,
    unsigned short* __restrict__ qo, unsigned short* __restrict__ kto,
    unsigned short* __restrict__ vo)
{
  constexpr int BPX = 3;                     // bcols per XCD (NN=3072)
  constexpr int KD  = 1024;

  __shared__ __align__(16) unsigned short smem[16384];   // 32 KB: a0|b0|a1|b1

  const int bid = blockIdx.x;
  const int xcd = bid & 7;
  const int t = bid >> 3;
  const int brow = t / BPX;
  const int bcol = xcd * BPX + t % BPX;

  const int tid = threadIdx.x;
  const int w = tid >> 6, lane = tid & 63;
  const int wr = w >> 1, wc = w & 1;
  const int lrow = lane & 15, g = lane >> 4;

  f32x4 acc[4][4];
#pragma unroll
  for (int i = 0; i < 4; ++i)
#pragma unroll
    for (int j = 0; j < 4; ++j) acc[i][j] = (f32x4){0.f, 0.f, 0.f, 0.f};

  const int r_in = lane >> 2;
  const int u = lane & 3;

  auto stage = [&](int kt) {
    unsigned short* a_lds = smem + ((kt & 1) ? 8192 : 0);
    unsigned short* b_lds = a_lds + 4096;
    const size_t kcol = (size_t)kt * 32 + u * 8;
    gload16(A + (size_t)(brow * 128 + 16 * w + r_in) * KD + kcol,       &a_lds[(16 * w) * 32]);
    gload16(A + (size_t)(brow * 128 + 16 * (w + 4) + r_in) * KD + kcol, &a_lds[(16 * (w + 4)) * 32]);
    gload16(B + (size_t)(bcol * 128 + 16 * w + r_in) * KD + kcol,       &b_lds[(16 * w) * 32]);
    gload16(B + (size_t)(bcol * 128 + 16 * (w + 4) + r_in) * KD + kcol, &b_lds[(16 * (w + 4)) * 32]);
  };

  const int KT = KD >> 5;
  stage(0);
  for (int kt = 0; kt < KT; ++kt) {
    __syncthreads();                         // buf[kt&1] staged; prev reads joined
    if (kt + 1 < KT) stage(kt + 1);          // early prefetch into buf^1
    const unsigned short* a_lds = smem + ((kt & 1) ? 8192 : 0);
    const unsigned short* b_lds = a_lds + 4096;
    bf16x8 af[4], bfr[4];
#pragma unroll
    for (int mt = 0; mt < 4; ++mt)
      af[mt] = *(const bf16x8*)&a_lds[(wr * 64 + mt * 16 + lrow) * 32 + g * 8];
#pragma unroll
    for (int nt = 0; nt < 4; ++nt)
      bfr[nt] = *(const bf16x8*)&b_lds[(wc * 64 + nt * 16 + lrow) * 32 + g * 8];
#pragma unroll
    for (int mt = 0; mt < 4; ++mt)
#pragma unroll
      for (int nt = 0; nt < 4; ++nt)
        acc[mt][nt] = mfma16(af[mt], bfr[nt], acc[mt][nt]);
  }

  __syncthreads();                           // all tile reads done before reuse
  const float qs = (bcol < 8) ? 0.125f : 1.0f;
#pragma unroll
  for (int nt = 0; nt < 4; ++nt) {
    const int c = bcol * 128 + wc * 64 + nt * 16 + lrow;
    const float bv = bias[c];
    const int lc = wc * 64 + nt * 16 + lrow;
#pragma unroll
    for (int mt = 0; mt < 4; ++mt) {
      const int lr0 = wr * 64 + mt * 16 + g * 4;
#pragma unroll
      for (int j = 0; j < 4; ++j)
        smem[(lr0 + j) * 128 + lc] = f2bf((acc[mt][nt][j] + bv) * qs);
    }
  }
  __syncthreads();
#pragma unroll
  for (int i = 0; i < 8; ++i) {
    const int unit = i * 256 + tid;          // 0..2047
    const int r = unit >> 4, cu = unit & 15;
    const u16x8 val = *(const u16x8*)&smem[r * 128 + cu * 8];
    const int m = brow * 128 + r;
    const int c = bcol * 128 + cu * 8;
    const int region = c >> 10, cl = c & 1023;
    if (region == 0)      *(u16x8*)&qo[(size_t)m * EE + cl] = val;
    else if (region == 2) *(u16x8*)&vo[(size_t)m * EE + cl] = val;
    else *(u16x8*)&kto[((size_t)((m & 7) * HH + (cl >> 6)) * LL + (m >> 3)) * DD + (cl & 63)] = val;
  }
}

// ---------------- out-proj GEMM (round-11 proven): BM=128, BN=256, fp32 out ----------------
__global__ __launch_bounds__(256, 2) void gemm_out(
    const unsigned short* __restrict__ A, const unsigned short* __restrict__ B,
    const float* __restrict__ bias, float* __restrict__ Cf)
{
  constexpr int KD = 1024;
  __shared__ __align__(16) unsigned short smem[24576];   // 48 KB: 2 x (A 4K + B 8K shorts)

  const int bid = blockIdx.x;
  const int q8 = gridDim.x >> 3;
  const int wgid = (bid & 7) * q8 + (bid >> 3);
  const int brow = wgid >> 2;                 // 64 brow x 4 bcol
  const int bcol = wgid & 3;

  const int tid = threadIdx.x;
  const int w = tid >> 6, lane = tid & 63;
  const int wr = w >> 1, wc = w & 1;
  const int lrow = lane & 15, g = lane >> 4;

  f32x4 acc[4][8];
#pragma unroll
  for (int i = 0; i < 4; ++i)
#pragma unroll
    for (int j = 0; j < 8; ++j) acc[i][j] = (f32x4){0.f, 0.f, 0.f, 0.f};

  const int r_in = lane >> 2;
  const int u = lane & 3;

  auto stage = [&](int kt) {
    unsigned short* base = smem + ((kt & 1) ? 12288 : 0);
    unsigned short* a_lds = base;
    unsigned short* b_lds = base + 4096;
    const size_t kcol = (size_t)kt * 32 + u * 8;
    gload16(A + (size_t)(brow * 128 + 16 * w + r_in) * KD + kcol,       &a_lds[(16 * w) * 32]);
    gload16(A + (size_t)(brow * 128 + 16 * (w + 4) + r_in) * KD + kcol, &a_lds[(16 * (w + 4)) * 32]);
#pragma unroll
    for (int i = 0; i < 4; ++i)
      gload16(B + (size_t)(bcol * 256 + 16 * (w + 4 * i) + r_in) * KD + kcol,
              &b_lds[(16 * (w + 4 * i)) * 32]);
  };

  const int KT = KD >> 5;
  stage(0);
  for (int kt = 0; kt < KT; ++kt) {
    __syncthreads();
    if (kt + 1 < KT) stage(kt + 1);
    const unsigned short* base = smem + ((kt & 1) ? 12288 : 0);
    const unsigned short* a_lds = base;
    const unsigned short* b_lds = base + 4096;
    bf16x8 af[4], bfr[8];
#pragma unroll
    for (int mt = 0; mt < 4; ++mt)
      af[mt] = *(const bf16x8*)&a_lds[(wr * 64 + mt * 16 + lrow) * 32 + g * 8];
#pragma unroll
    for (int nt = 0; nt < 8; ++nt)
      bfr[nt] = *(const bf16x8*)&b_lds[(wc * 128 + nt * 16 + lrow) * 32 + g * 8];
#pragma unroll
    for (int mt = 0; mt < 4; ++mt)
#pragma unroll
      for (int nt = 0; nt < 8; ++nt)
        acc[mt][nt] = mfma16(af[mt], bfr[nt], acc[mt][nt]);
  }

#pragma unroll
  for (int nt = 0; nt < 8; ++nt) {
    const int c = bcol * 256 + wc * 128 + nt * 16 + lrow;
    const float bv = bias[c];
#pragma unroll
    for (int mt = 0; mt < 4; ++mt) {
      const int m0 = brow * 128 + wr * 64 + mt * 16 + g * 4;
#pragma unroll
      for (int j = 0; j < 4; ++j)
        Cf[(size_t)(m0 + j) * 1024 + c] = acc[mt][nt][j] + bv;
    }
  }
}

// ---------------- V transpose: v[m][1024] -> vt[n][h][d][s] ----------------
__global__ void transpose_v(const unsigned short* __restrict__ v, unsigned short* __restrict__ vt) {
  __shared__ __align__(16) unsigned short tile[64][68];
  const int b = blockIdx.x;                 // 2048
  const int lchunk = b & 15, h = (b >> 4) & 15, n = b >> 8;
  const int t = threadIdx.x;
  const int c4 = (t & 15) * 4, r = t >> 4;
#pragma unroll
  for (int p = 0; p < 4; ++p) {
    const int l = lchunk * 64 + p * 16 + r;
    u16x4 x = *(const u16x4*)&v[(size_t)(l * NB + n) * EE + h * DD + c4];
    *(u16x4*)&tile[p * 16 + r][c4] = x;
  }
  __syncthreads();
#pragma unroll
  for (int p = 0; p < 4; ++p) {
    const int d = p * 16 + r;
    u16x4 o;
#pragma unroll
    for (int i = 0; i < 4; ++i) o[i] = tile[c4 + i][d];
    *(u16x4*)&vt[((size_t)(n * HH + h) * DD + d) * LL + lchunk * 64 + c4] = o;
  }
}

// ---------------- flash attention (single pass, unnormalized accum) ----------------
// grid 512 = n(8, XCD) x h(16) x ltile(4 of 256 rows); block 256 = 4 waves.
__global__ __launch_bounds__(256) void attn_flash(
    const unsigned short* __restrict__ q,    // [m][1024] bf16, pre-scaled by 0.125
    const unsigned short* __restrict__ kt,   // [n][h][s][64]
    const unsigned short* __restrict__ vt,   // [n][h][64][1024]
    unsigned short* __restrict__ ctxo,       // [m][1024] bf16
    float* __restrict__ rinvb)               // [n][h][1024]
{
  __shared__ __align__(16) unsigned short kc[2][64][64];      // 16 KB, swizzled
  __shared__ __align__(16) unsigned short pl[4][4][16][72];   // 36.9 KB [wave][tile][l][s]

  const int bid = blockIdx.x;
  const int n = bid & 7;
  const int rest = bid >> 3;        // 0..63
  const int h = rest >> 2;          // 0..15
  const int lt = (rest & 3) << 8;   // 0, 256, 512, 768
  const int tid = threadIdx.x;
  const int wv = tid >> 6, lane = tid & 63;
  const int ll = lane & 15, g = lane >> 4;
  const int a3 = ll & 7;

  bf16x8 qf0[4], qf1[4];
#pragma unroll
  for (int T = 0; T < 4; ++T) {
    const int lr = lt + T * 64 + wv * 16 + ll;
    const unsigned short* qp = q + ((size_t)lr * NB + n) * EE + h * DD + g * 8;
    qf0[T] = *(const bf16x8*)qp;
    qf1[T] = *(const bf16x8*)(qp + 32);
  }

  const unsigned short* kslab = kt + (size_t)(n * HH + h) * LL * DD;
  const unsigned short* vbase = vt + (size_t)(n * HH + h) * DD * LL;

  const int r8 = lane >> 3;
  const int c16 = (lane & 7) ^ r8;
  const int kof0 = ll * 128 + ((g ^ a3) << 4);
  const int kof1 = ll * 128 + (((4 + g) ^ a3) << 4);

  auto stageK = [&](int buf, int ch) {
    unsigned short* kd = &kc[buf][wv * 16][0];
    const unsigned short* src = kslab + (size_t)(ch * 64 + wv * 16) * DD;
    gload16(src + (size_t)r8 * DD + c16 * 8,       kd);
    gload16(src + (size_t)(8 + r8) * DD + c16 * 8, kd + 8 * 64);
  };

  f32x4 ctx[4][4];
  f32x4 sum[4];
#pragma unroll
  for (int T = 0; T < 4; ++T) {
    sum[T] = (f32x4){0.f, 0.f, 0.f, 0.f};
#pragma unroll
    for (int dt = 0; dt < 4; ++dt) ctx[T][dt] = (f32x4){0.f, 0.f, 0.f, 0.f};
  }

  char* plb = (char*)&pl[wv][0][0][0];

  stageK(0, 0);
  for (int ch = 0; ch < 16; ++ch) {
    __syncthreads();
    const int buf = ch & 1;
    const char* kb = (const char*)&kc[buf][0][0];

    bf16x8 vf0[4], vf1[4];
#pragma unroll
    for (int dt = 0; dt < 4; ++dt) {
      const unsigned short* vp = vbase + (size_t)(dt * 16 + ll) * LL + ch * 64 + g * 8;
      vf0[dt] = *(const bf16x8*)vp;
      vf1[dt] = *(const bf16x8*)(vp + 32);
    }
    if (ch < 15) stageK(buf ^ 1, ch + 1);

#pragma unroll
    for (int t = 0; t < 4; ++t) {
      const bf16x8 kf0 = *(const bf16x8*)(kb + t * 2048 + kof0);
      const bf16x8 kf1 = *(const bf16x8*)(kb + t * 2048 + kof1);
#pragma unroll
      for (int T = 0; T < 4; ++T) {
        f32x4 sc = (f32x4){0.f, 0.f, 0.f, 0.f};
        sc = mfma16(kf0, qf0[T], sc);
        sc = mfma16(kf1, qf1[T], sc);
        f32x4 p;
#pragma unroll
        for (int j = 0; j < 4; ++j) p[j] = __expf(sc[j]);
        sum[T] += p;
        uint2 wT; wT.x = cvtpk(p[0], p[1]); wT.y = cvtpk(p[2], p[3]);
        *(uint2*)(plb + T * 2304 + ll * 144 + (t * 16 + g * 4) * 2) = wT;
      }
    }
#pragma unroll
    for (int T = 0; T < 4; ++T) {
      const bf16x8 pf0 = *(const bf16x8*)(plb + T * 2304 + ll * 144 + g * 16);
      const bf16x8 pf1 = *(const bf16x8*)(plb + T * 2304 + ll * 144 + 64 + g * 16);
#pragma unroll
      for (int dt = 0; dt < 4; ++dt) {
        ctx[T][dt] = mfma16(vf0[dt], pf0, ctx[T][dt]);
        ctx[T][dt] = mfma16(vf1[dt], pf1, ctx[T][dt]);
      }
    }
  }

#pragma unroll
  for (int T = 0; T < 4; ++T) {
    float s1 = sum[T][0] + sum[T][1] + sum[T][2] + sum[T][3];
    s1 += __shfl_xor(s1, 16); s1 += __shfl_xor(s1, 32);
    const float rinv = 1.0f / s1;
    if (lane < 16) rinvb[(size_t)(n * HH + h) * LL + lt + T * 64 + wv * 16 + lane] = rinv;
    const int lr = lt + T * 64 + wv * 16 + ll;
    unsigned short* cp = ctxo + ((size_t)lr * NB + n) * EE + h * DD;
#pragma unroll
    for (int dt = 0; dt < 4; ++dt) {
      uint2 o;
      o.x = cvtpk(ctx[T][dt][0] * rinv, ctx[T][dt][1] * rinv);
      o.y = cvtpk(ctx[T][dt][2] * rinv, ctx[T][dt][3] * rinv);
      *(uint2*)(cp + dt * 16 + g * 4) = o;
    }
  }
}

// ---------------- head-mean attention output (recompute QK with known rinv) ----------------
__global__ __launch_bounds__(256) void attn_mean(
    const unsigned short* __restrict__ q,    // [m][1024] bf16, pre-scaled by 0.125
    const unsigned short* __restrict__ kt,   // [n][h][s][64]
    const float* __restrict__ rinvb,         // [n][h][1024]
    float* __restrict__ attn_out)            // [n][1024][1024]
{
  __shared__ __align__(16) unsigned short kc[2][128][64];  // 32KB, swizzled

  const int bid = blockIdx.x;
  const int n = bid & 7;
  const int r = bid >> 3;
  const int sh = r & 7;
  const int lt = (r >> 3) << 6;
  const int tid = threadIdx.x;
  const int wv = tid >> 6, lane = tid & 63;
  const int ll = lane & 15, g = lane >> 4;
  const int a3 = ll & 7;
  const int sb = sh << 7;
  const int lrow = lt + wv * 16 + ll;

  const int r8 = lane >> 3;
  const int c16 = (lane & 7) ^ r8;
  const int kof0 = ll * 128 + ((g ^ a3) << 4);
  const int kof1 = ll * 128 + (((4 + g) ^ a3) << 4);

  const unsigned short* kwin = kt + (size_t)n * HH * LL * DD + (size_t)sb * DD;

  auto stage = [&](int buf, int h) {
    unsigned short* kd = &kc[buf][wv * 32][0];
    const unsigned short* src = kwin + (size_t)h * LL * DD + (size_t)(wv * 32) * DD;
#pragma unroll
    for (int i = 0; i < 4; ++i)
      gload16(src + (size_t)(i * 8 + r8) * DD + c16 * 8, kd + i * 8 * 64);
  };

  float rv[16];
#pragma unroll
  for (int h = 0; h < HH; ++h) rv[h] = rinvb[(size_t)(n * HH + h) * LL + lrow];

  const unsigned short* qb2 = q + ((size_t)lrow * NB + n) * EE + g * 8;

  f32x4 acc[8];
#pragma unroll
  for (int i = 0; i < 8; ++i) acc[i] = (f32x4){0.f, 0.f, 0.f, 0.f};

  stage(0, 0);
  for (int h = 0; h < HH; ++h) {
    __syncthreads();
    const char* kb = (const char*)&kc[h & 1][0][0];
    const unsigned short* qp = qb2 + h * DD;
    const bf16x8 qf0 = *(const bf16x8*)qp;
    const bf16x8 qf1 = *(const bf16x8*)(qp + 32);
    if (h + 1 < HH) stage((h + 1) & 1, h + 1);
    const float rvh = rv[h];
#pragma unroll
    for (int t = 0; t < 8; ++t) {
      bf16x8 kf0 = *(const bf16x8*)(kb + t * 2048 + kof0);
      bf16x8 kf1 = *(const bf16x8*)(kb + t * 2048 + kof1);
      f32x4 sc = (f32x4){0.f, 0.f, 0.f, 0.f};
      sc = mfma16(kf0, qf0, sc);
      sc = mfma16(kf1, qf1, sc);
#pragma unroll
      for (int j = 0; j < 4; ++j) acc[t][j] += __expf(sc[j]) * rvh;
    }
  }

  float* ap = attn_out + ((size_t)n * LL + lrow) * LL + sb + g * 4;
#pragma unroll
  for (int t = 0; t < 8; ++t) *(f32x4*)(ap + t * 16) = acc[t] * 0.0625f;
}

extern "C" void kernel_launch(void* const* d_in, const int* in_sizes, int n_in,
                              void* d_out, int out_size, void* d_ws, size_t ws_size,
                              hipStream_t stream) {
  const float* x   = (const float*)d_in[0];
  const float* win = (const float*)d_in[1];
  const float* bin = (const float*)d_in[2];
  const float* ow  = (const float*)d_in[3];
  const float* ob  = (const float*)d_in[4];
  float* out = (float*)d_out;

  const size_t need = ((size_t)MM * EE * 5 + (size_t)K3 * EE + (size_t)EE * EE) * 2
                    + (size_t)NB * HH * LL * 4;
  if (ws_size < need) return;

  unsigned short* ws  = (unsigned short*)d_ws;
  unsigned short* xb  = ws;                        // [8192][1024]  (reused as ctx)
  unsigned short* wb  = xb + (size_t)MM * EE;      // [3072][1024]
  unsigned short* owb = wb + (size_t)K3 * EE;      // [1024][1024]
  unsigned short* qb  = owb + (size_t)EE * EE;     // [8192][1024]
  unsigned short* ktb = qb + (size_t)MM * EE;      // [8][16][1024][64]
  unsigned short* vb  = ktb + (size_t)MM * EE;     // [8192][1024]
  unsigned short* vtb = vb + (size_t)MM * EE;      // [8][16][64][1024]
  float* rinvb = (float*)(vtb + (size_t)MM * EE);  // [8][16][1024]
  unsigned short* ctx = xb;

  cvt3_kernel<<<2048, 256, 0, stream>>>(x, win, ow, xb, wb, owb);
  gemm_in<<<1536, 256, 0, stream>>>(xb, wb, bin, qb, ktb, vb);
  transpose_v<<<2048, 256, 0, stream>>>(vb, vtb);
  attn_flash<<<512, 256, 0, stream>>>(qb, ktb, vtb, ctx, rinvb);
  attn_mean<<<1024, 256, 0, stream>>>(qb, ktb, rinvb, out + (size_t)MM * EE);
  gemm_out<<<256, 256, 0, stream>>>(ctx, owb, ob, out);
}

// Round 14
// 203.116 us; speedup vs baseline: 1.0178x; 1.0178x over previous
//
#include <hip/hip_runtime.h>
#include <stdint.h>

#define LL 1024
#define NB 8
#define EE 1024
#define HH 16
#define DD 64
#define MM (LL*NB)      // 8192 rows (l*NB+n)
#define K3 (3*EE)       // 3072

typedef __attribute__((ext_vector_type(8))) short bf16x8;   // 8 bf16 in 4 VGPRs
typedef __attribute__((ext_vector_type(4))) float f32x4;
typedef __attribute__((ext_vector_type(4))) unsigned short u16x4;
typedef __attribute__((ext_vector_type(8))) unsigned short u16x8;

__device__ __forceinline__ unsigned short f2bf(float f) {
  uint32_t u = __builtin_bit_cast(uint32_t, f);
  u += 0x7fffu + ((u >> 16) & 1u);           // RNE
  return (unsigned short)(u >> 16);
}
// HW RNE pack: dst = [bf16(hi)|bf16(lo)] — bit-identical to f2bf pairs
__device__ __forceinline__ uint32_t cvtpk(float lo, float hi) {
  uint32_t d;
  asm volatile("v_cvt_pk_bf16_f32 %0, %1, %2" : "=v"(d) : "v"(lo), "v"(hi));
  return d;
}
__device__ __forceinline__ f32x4 mfma16(bf16x8 a, bf16x8 b, f32x4 c) {
  return __builtin_amdgcn_mfma_f32_16x16x32_bf16(a, b, c, 0, 0, 0);
}
__device__ __forceinline__ void gload16(const unsigned short* src, unsigned short* dst) {
  __builtin_amdgcn_global_load_lds(
      (const __attribute__((address_space(1))) uint32_t*)src,
      (__attribute__((address_space(3))) uint32_t*)dst, 16, 0, 0);
}

// ---------------- fp32 -> bf16 convert (all three inputs, one launch) ----------------
__global__ void cvt3_kernel(const float* __restrict__ a, const float* __restrict__ b,
                            const float* __restrict__ c,
                            unsigned short* __restrict__ da, unsigned short* __restrict__ db,
                            unsigned short* __restrict__ dc) {
  const int NA = (MM * EE) / 4, NBq = (K3 * EE) / 4, NC = (EE * EE) / 4;
  const int total = NA + NBq + NC;
  for (int i = blockIdx.x * blockDim.x + threadIdx.x; i < total; i += gridDim.x * blockDim.x) {
    const float* s; unsigned short* d; int j;
    if (i < NA)            { s = a; d = da; j = i; }
    else if (i < NA + NBq) { s = b; d = db; j = i - NA; }
    else                   { s = c; d = dc; j = i - NA - NBq; }
    f32x4 v = ((const f32x4*)s)[j];
    u16x4 o;
    o[0] = f2bf(v[0]); o[1] = f2bf(v[1]); o[2] = f2bf(v[2]); o[3] = f2bf(v[3]);
    ((u16x4*)d)[j] = o;
  }
}

// ---------------- in-proj GEMM (round-10 proven, 82 us): 128x128 tile ----------------
// C[m][c] = sum_k A[m][k]*W[c][k] + bias[c]; bf16 out via LDS-coalesced epilogue:
//   c in [0,1024)    -> qo[m][c] * 0.125 (exact)
//   c in [1024,2048) -> kto[n][h][l][d]
//   c in [2048,3072) -> vo[m][c-2048]
// Double-buffered 32KB LDS, 1 barrier/K-step, stage issued right after it.
__global__ __launch_bounds__(256) void gemm_in(
    const unsigned short* __restrict__ A, const unsigned short* __restrict__ B,
    const float* __restrict__ bias,
    unsigned short* __restrict__ qo, unsigned short* __restrict__ kto,
    unsigned short* __restrict__ vo)
{
  constexpr int BPX = 3;                     // bcols per XCD (NN=3072)
  constexpr int KD  = 1024;

  __shared__ __align__(16) unsigned short smem[16384];   // 32 KB: a0|b0|a1|b1

  const int bid = blockIdx.x;
  const int xcd = bid & 7;
  const int t = bid >> 3;
  const int brow = t / BPX;
  const int bcol = xcd * BPX + t % BPX;

  const int tid = threadIdx.x;
  const int w = tid >> 6, lane = tid & 63;
  const int wr = w >> 1, wc = w & 1;
  const int lrow = lane & 15, g = lane >> 4;

  f32x4 acc[4][4];
#pragma unroll
  for (int i = 0; i < 4; ++i)
#pragma unroll
    for (int j = 0; j < 4; ++j) acc[i][j] = (f32x4){0.f, 0.f, 0.f, 0.f};

  const int r_in = lane >> 2;
  const int u = lane & 3;

  auto stage = [&](int kt) {
    unsigned short* a_lds = smem + ((kt & 1) ? 8192 : 0);
    unsigned short* b_lds = a_lds + 4096;
    const size_t kcol = (size_t)kt * 32 + u * 8;
    gload16(A + (size_t)(brow * 128 + 16 * w + r_in) * KD + kcol,       &a_lds[(16 * w) * 32]);
    gload16(A + (size_t)(brow * 128 + 16 * (w + 4) + r_in) * KD + kcol, &a_lds[(16 * (w + 4)) * 32]);
    gload16(B + (size_t)(bcol * 128 + 16 * w + r_in) * KD + kcol,       &b_lds[(16 * w) * 32]);
    gload16(B + (size_t)(bcol * 128 + 16 * (w + 4) + r_in) * KD + kcol, &b_lds[(16 * (w + 4)) * 32]);
  };

  const int KT = KD >> 5;
  stage(0);
  for (int kt = 0; kt < KT; ++kt) {
    __syncthreads();                         // buf[kt&1] staged; prev reads joined
    if (kt + 1 < KT) stage(kt + 1);          // early prefetch into buf^1
    const unsigned short* a_lds = smem + ((kt & 1) ? 8192 : 0);
    const unsigned short* b_lds = a_lds + 4096;
    bf16x8 af[4], bfr[4];
#pragma unroll
    for (int mt = 0; mt < 4; ++mt)
      af[mt] = *(const bf16x8*)&a_lds[(wr * 64 + mt * 16 + lrow) * 32 + g * 8];
#pragma unroll
    for (int nt = 0; nt < 4; ++nt)
      bfr[nt] = *(const bf16x8*)&b_lds[(wc * 64 + nt * 16 + lrow) * 32 + g * 8];
#pragma unroll
    for (int mt = 0; mt < 4; ++mt)
#pragma unroll
      for (int nt = 0; nt < 4; ++nt)
        acc[mt][nt] = mfma16(af[mt], bfr[nt], acc[mt][nt]);
  }

  __syncthreads();                           // all tile reads done before reuse
  const float qs = (bcol < 8) ? 0.125f : 1.0f;
#pragma unroll
  for (int nt = 0; nt < 4; ++nt) {
    const int c = bcol * 128 + wc * 64 + nt * 16 + lrow;
    const float bv = bias[c];
    const int lc = wc * 64 + nt * 16 + lrow;
#pragma unroll
    for (int mt = 0; mt < 4; ++mt) {
      const int lr0 = wr * 64 + mt * 16 + g * 4;
#pragma unroll
      for (int j = 0; j < 4; ++j)
        smem[(lr0 + j) * 128 + lc] = f2bf((acc[mt][nt][j] + bv) * qs);
    }
  }
  __syncthreads();
#pragma unroll
  for (int i = 0; i < 8; ++i) {
    const int unit = i * 256 + tid;          // 0..2047
    const int r = unit >> 4, cu = unit & 15;
    const u16x8 val = *(const u16x8*)&smem[r * 128 + cu * 8];
    const int m = brow * 128 + r;
    const int c = bcol * 128 + cu * 8;
    const int region = c >> 10, cl = c & 1023;
    if (region == 0)      *(u16x8*)&qo[(size_t)m * EE + cl] = val;
    else if (region == 2) *(u16x8*)&vo[(size_t)m * EE + cl] = val;
    else *(u16x8*)&kto[((size_t)((m & 7) * HH + (cl >> 6)) * LL + (m >> 3)) * DD + (cl & 63)] = val;
  }
}

// ---------------- V transpose: v[m][1024] -> vt[n][h][d][s] ----------------
__global__ void transpose_v(const unsigned short* __restrict__ v, unsigned short* __restrict__ vt) {
  __shared__ __align__(16) unsigned short tile[64][68];
  const int b = blockIdx.x;                 // 2048
  const int lchunk = b & 15, h = (b >> 4) & 15, n = b >> 8;
  const int t = threadIdx.x;
  const int c4 = (t & 15) * 4, r = t >> 4;
#pragma unroll
  for (int p = 0; p < 4; ++p) {
    const int l = lchunk * 64 + p * 16 + r;
    u16x4 x = *(const u16x4*)&v[(size_t)(l * NB + n) * EE + h * DD + c4];
    *(u16x4*)&tile[p * 16 + r][c4] = x;
  }
  __syncthreads();
#pragma unroll
  for (int p = 0; p < 4; ++p) {
    const int d = p * 16 + r;
    u16x4 o;
#pragma unroll
    for (int i = 0; i < 4; ++i) o[i] = tile[c4 + i][d];
    *(u16x4*)&vt[((size_t)(n * HH + h) * DD + d) * LL + lchunk * 64 + c4] = o;
  }
}

// ---------------- flash attention (single pass, unnormalized accum) ----------------
// grid 512 = n(8, XCD) x h(16) x ltile(4 of 256 rows); block 256 = 4 waves.
__global__ __launch_bounds__(256) void attn_flash(
    const unsigned short* __restrict__ q,    // [m][1024] bf16, pre-scaled by 0.125
    const unsigned short* __restrict__ kt,   // [n][h][s][64]
    const unsigned short* __restrict__ vt,   // [n][h][64][1024]
    unsigned short* __restrict__ ctxo,       // [m][1024] bf16
    float* __restrict__ rinvb)               // [n][h][1024]
{
  __shared__ __align__(16) unsigned short kc[2][64][64];      // 16 KB, swizzled
  __shared__ __align__(16) unsigned short pl[4][4][16][72];   // 36.9 KB [wave][tile][l][s]

  const int bid = blockIdx.x;
  const int n = bid & 7;
  const int rest = bid >> 3;        // 0..63
  const int h = rest >> 2;          // 0..15
  const int lt = (rest & 3) << 8;   // 0, 256, 512, 768
  const int tid = threadIdx.x;
  const int wv = tid >> 6, lane = tid & 63;
  const int ll = lane & 15, g = lane >> 4;
  const int a3 = ll & 7;

  bf16x8 qf0[4], qf1[4];
#pragma unroll
  for (int T = 0; T < 4; ++T) {
    const int lr = lt + T * 64 + wv * 16 + ll;
    const unsigned short* qp = q + ((size_t)lr * NB + n) * EE + h * DD + g * 8;
    qf0[T] = *(const bf16x8*)qp;
    qf1[T] = *(const bf16x8*)(qp + 32);
  }

  const unsigned short* kslab = kt + (size_t)(n * HH + h) * LL * DD;
  const unsigned short* vbase = vt + (size_t)(n * HH + h) * DD * LL;

  const int r8 = lane >> 3;
  const int c16 = (lane & 7) ^ r8;
  const int kof0 = ll * 128 + ((g ^ a3) << 4);
  const int kof1 = ll * 128 + (((4 + g) ^ a3) << 4);

  auto stageK = [&](int buf, int ch) {
    unsigned short* kd = &kc[buf][wv * 16][0];
    const unsigned short* src = kslab + (size_t)(ch * 64 + wv * 16) * DD;
    gload16(src + (size_t)r8 * DD + c16 * 8,       kd);
    gload16(src + (size_t)(8 + r8) * DD + c16 * 8, kd + 8 * 64);
  };

  f32x4 ctx[4][4];
  f32x4 sum[4];
#pragma unroll
  for (int T = 0; T < 4; ++T) {
    sum[T] = (f32x4){0.f, 0.f, 0.f, 0.f};
#pragma unroll
    for (int dt = 0; dt < 4; ++dt) ctx[T][dt] = (f32x4){0.f, 0.f, 0.f, 0.f};
  }

  char* plb = (char*)&pl[wv][0][0][0];

  stageK(0, 0);
  for (int ch = 0; ch < 16; ++ch) {
    __syncthreads();
    const int buf = ch & 1;
    const char* kb = (const char*)&kc[buf][0][0];

    bf16x8 vf0[4], vf1[4];
#pragma unroll
    for (int dt = 0; dt < 4; ++dt) {
      const unsigned short* vp = vbase + (size_t)(dt * 16 + ll) * LL + ch * 64 + g * 8;
      vf0[dt] = *(const bf16x8*)vp;
      vf1[dt] = *(const bf16x8*)(vp + 32);
    }
    if (ch < 15) stageK(buf ^ 1, ch + 1);

#pragma unroll
    for (int t = 0; t < 4; ++t) {
      const bf16x8 kf0 = *(const bf16x8*)(kb + t * 2048 + kof0);
      const bf16x8 kf1 = *(const bf16x8*)(kb + t * 2048 + kof1);
#pragma unroll
      for (int T = 0; T < 4; ++T) {
        f32x4 sc = (f32x4){0.f, 0.f, 0.f, 0.f};
        sc = mfma16(kf0, qf0[T], sc);
        sc = mfma16(kf1, qf1[T], sc);
        f32x4 p;
#pragma unroll
        for (int j = 0; j < 4; ++j) p[j] = __expf(sc[j]);
        sum[T] += p;
        uint2 wT; wT.x = cvtpk(p[0], p[1]); wT.y = cvtpk(p[2], p[3]);
        *(uint2*)(plb + T * 2304 + ll * 144 + (t * 16 + g * 4) * 2) = wT;
      }
    }
#pragma unroll
    for (int T = 0; T < 4; ++T) {
      const bf16x8 pf0 = *(const bf16x8*)(plb + T * 2304 + ll * 144 + g * 16);
      const bf16x8 pf1 = *(const bf16x8*)(plb + T * 2304 + ll * 144 + 64 + g * 16);
#pragma unroll
      for (int dt = 0; dt < 4; ++dt) {
        ctx[T][dt] = mfma16(vf0[dt], pf0, ctx[T][dt]);
        ctx[T][dt] = mfma16(vf1[dt], pf1, ctx[T][dt]);
      }
    }
  }

#pragma unroll
  for (int T = 0; T < 4; ++T) {
    float s1 = sum[T][0] + sum[T][1] + sum[T][2] + sum[T][3];
    s1 += __shfl_xor(s1, 16); s1 += __shfl_xor(s1, 32);
    const float rinv = 1.0f / s1;
    if (lane < 16) rinvb[(size_t)(n * HH + h) * LL + lt + T * 64 + wv * 16 + lane] = rinv;
    const int lr = lt + T * 64 + wv * 16 + ll;
    unsigned short* cp = ctxo + ((size_t)lr * NB + n) * EE + h * DD;
#pragma unroll
    for (int dt = 0; dt < 4; ++dt) {
      uint2 o;
      o.x = cvtpk(ctx[T][dt][0] * rinv, ctx[T][dt][1] * rinv);
      o.y = cvtpk(ctx[T][dt][2] * rinv, ctx[T][dt][3] * rinv);
      *(uint2*)(cp + dt * 16 + g * 4) = o;
    }
  }
}

// ======== fused: head-mean attention output (blocks 0..1023) + out-proj GEMM (1024..1535) ========
// Both paths use exactly 32 KB LDS and 256 threads; independent inputs/outputs.
__global__ __launch_bounds__(256) void mean_out(
    const unsigned short* __restrict__ q,    // [m][1024] bf16, pre-scaled by 0.125
    const unsigned short* __restrict__ kt,   // [n][h][s][64]
    const float* __restrict__ rinvb,         // [n][h][1024]
    float* __restrict__ attn_out,            // [n][1024][1024]
    const unsigned short* __restrict__ ctx,  // [m][1024] bf16
    const unsigned short* __restrict__ ow,   // [1024][1024] bf16 (row = out col)
    const float* __restrict__ ob,
    float* __restrict__ out)                 // [m][1024] fp32
{
  __shared__ __align__(16) unsigned short smem[16384];   // 32 KB, both paths

  const int bid = blockIdx.x;
  const int tid = threadIdx.x;
  const int wv = tid >> 6, lane = tid & 63;
  const int ll = lane & 15, g = lane >> 4;

  if (bid < 1024) {
    // ---------------- head-mean path (round-13 attn_mean body) ----------------
    unsigned short (*kc)[128][64] = (unsigned short (*)[128][64])smem;
    const int n = bid & 7;
    const int r = bid >> 3;
    const int sh = r & 7;
    const int lt = (r >> 3) << 6;
    const int a3 = ll & 7;
    const int sb = sh << 7;
    const int lrow = lt + wv * 16 + ll;

    const int r8 = lane >> 3;
    const int c16 = (lane & 7) ^ r8;
    const int kof0 = ll * 128 + ((g ^ a3) << 4);
    const int kof1 = ll * 128 + (((4 + g) ^ a3) << 4);

    const unsigned short* kwin = kt + (size_t)n * HH * LL * DD + (size_t)sb * DD;

    auto stage = [&](int buf, int h) {
      unsigned short* kd = &kc[buf][wv * 32][0];
      const unsigned short* src = kwin + (size_t)h * LL * DD + (size_t)(wv * 32) * DD;
#pragma unroll
      for (int i = 0; i < 4; ++i)
        gload16(src + (size_t)(i * 8 + r8) * DD + c16 * 8, kd + i * 8 * 64);
    };

    float rv[16];
#pragma unroll
    for (int h = 0; h < HH; ++h) rv[h] = rinvb[(size_t)(n * HH + h) * LL + lrow];

    const unsigned short* qb2 = q + ((size_t)lrow * NB + n) * EE + g * 8;

    f32x4 acc[8];
#pragma unroll
    for (int i = 0; i < 8; ++i) acc[i] = (f32x4){0.f, 0.f, 0.f, 0.f};

    stage(0, 0);
    for (int h = 0; h < HH; ++h) {
      __syncthreads();
      const char* kb = (const char*)&kc[h & 1][0][0];
      const unsigned short* qp = qb2 + h * DD;
      const bf16x8 qf0 = *(const bf16x8*)qp;
      const bf16x8 qf1 = *(const bf16x8*)(qp + 32);
      if (h + 1 < HH) stage((h + 1) & 1, h + 1);
      const float rvh = rv[h];
#pragma unroll
      for (int t = 0; t < 8; ++t) {
        bf16x8 kf0 = *(const bf16x8*)(kb + t * 2048 + kof0);
        bf16x8 kf1 = *(const bf16x8*)(kb + t * 2048 + kof1);
        f32x4 sc = (f32x4){0.f, 0.f, 0.f, 0.f};
        sc = mfma16(kf0, qf0, sc);
        sc = mfma16(kf1, qf1, sc);
#pragma unroll
        for (int j = 0; j < 4; ++j) acc[t][j] += __expf(sc[j]) * rvh;
      }
    }

    float* ap = attn_out + ((size_t)n * LL + lrow) * LL + sb + g * 4;
#pragma unroll
    for (int t = 0; t < 8; ++t) *(f32x4*)(ap + t * 16) = acc[t] * 0.0625f;

  } else {
    // ---------------- out-proj path (round-10 proven 128x128 MODE-0 body) ----------------
    const int b2 = bid - 1024;                // 0..511
    const int wgid = (b2 & 7) * 64 + (b2 >> 3);   // XCD-chunked bijective
    const int brow = wgid & 63;
    const int bcol = wgid >> 6;               // 0..7: one W panel per XCD

    const int w = wv;
    const int wr = w >> 1, wc = w & 1;
    const int lrow = ll;

    f32x4 acc[4][4];
#pragma unroll
    for (int i = 0; i < 4; ++i)
#pragma unroll
      for (int j = 0; j < 4; ++j) acc[i][j] = (f32x4){0.f, 0.f, 0.f, 0.f};

    const int r_in = lane >> 2;
    const int u = lane & 3;

    auto stage = [&](int kt2) {
      unsigned short* a_lds = smem + ((kt2 & 1) ? 8192 : 0);
      unsigned short* b_lds = a_lds + 4096;
      const size_t kcol = (size_t)kt2 * 32 + u * 8;
      gload16(ctx + (size_t)(brow * 128 + 16 * w + r_in) * 1024 + kcol,       &a_lds[(16 * w) * 32]);
      gload16(ctx + (size_t)(brow * 128 + 16 * (w + 4) + r_in) * 1024 + kcol, &a_lds[(16 * (w + 4)) * 32]);
      gload16(ow + (size_t)(bcol * 128 + 16 * w + r_in) * 1024 + kcol,        &b_lds[(16 * w) * 32]);
      gload16(ow + (size_t)(bcol * 128 + 16 * (w + 4) + r_in) * 1024 + kcol,  &b_lds[(16 * (w + 4)) * 32]);
    };

    stage(0);
    for (int kt2 = 0; kt2 < 32; ++kt2) {
      __syncthreads();
      if (kt2 + 1 < 32) stage(kt2 + 1);
      const unsigned short* a_lds = smem + ((kt2 & 1) ? 8192 : 0);
      const unsigned short* b_lds = a_lds + 4096;
      bf16x8 af[4], bfr[4];
#pragma unroll
      for (int mt = 0; mt < 4; ++mt)
        af[mt] = *(const bf16x8*)&a_lds[(wr * 64 + mt * 16 + lrow) * 32 + g * 8];
#pragma unroll
      for (int nt = 0; nt < 4; ++nt)
        bfr[nt] = *(const bf16x8*)&b_lds[(wc * 64 + nt * 16 + lrow) * 32 + g * 8];
#pragma unroll
      for (int mt = 0; mt < 4; ++mt)
#pragma unroll
        for (int nt = 0; nt < 4; ++nt)
          acc[mt][nt] = mfma16(af[mt], bfr[nt], acc[mt][nt]);
    }

#pragma unroll
    for (int nt = 0; nt < 4; ++nt) {
      const int c = bcol * 128 + wc * 64 + nt * 16 + lrow;
      const float bv = ob[c];
#pragma unroll
      for (int mt = 0; mt < 4; ++mt) {
        const int m0 = brow * 128 + wr * 64 + mt * 16 + g * 4;
#pragma unroll
        for (int j = 0; j < 4; ++j)
          out[(size_t)(m0 + j) * 1024 + c] = acc[mt][nt][j] + bv;
      }
    }
  }
}

extern "C" void kernel_launch(void* const* d_in, const int* in_sizes, int n_in,
                              void* d_out, int out_size, void* d_ws, size_t ws_size,
                              hipStream_t stream) {
  const float* x   = (const float*)d_in[0];
  const float* win = (const float*)d_in[1];
  const float* bin = (const float*)d_in[2];
  const float* ow  = (const float*)d_in[3];
  const float* ob  = (const float*)d_in[4];
  float* out = (float*)d_out;

  const size_t need = ((size_t)MM * EE * 5 + (size_t)K3 * EE + (size_t)EE * EE) * 2
                    + (size_t)NB * HH * LL * 4;
  if (ws_size < need) return;

  unsigned short* ws  = (unsigned short*)d_ws;
  unsigned short* xb  = ws;                        // [8192][1024]  (reused as ctx)
  unsigned short* wb  = xb + (size_t)MM * EE;      // [3072][1024]
  unsigned short* owb = wb + (size_t)K3 * EE;      // [1024][1024]
  unsigned short* qb  = owb + (size_t)EE * EE;     // [8192][1024]
  unsigned short* ktb = qb + (size_t)MM * EE;      // [8][16][1024][64]
  unsigned short* vb  = ktb + (size_t)MM * EE;     // [8192][1024]
  unsigned short* vtb = vb + (size_t)MM * EE;      // [8][16][64][1024]
  float* rinvb = (float*)(vtb + (size_t)MM * EE);  // [8][16][1024]
  unsigned short* ctx = xb;

  cvt3_kernel<<<2048, 256, 0, stream>>>(x, win, ow, xb, wb, owb);
  gemm_in<<<1536, 256, 0, stream>>>(xb, wb, bin, qb, ktb, vb);
  transpose_v<<<2048, 256, 0, stream>>>(vb, vtb);
  attn_flash<<<512, 256, 0, stream>>>(qb, ktb, vtb, ctx, rinvb);
  mean_out<<<1536, 256, 0, stream>>>(qb, ktb, rinvb, out + (size_t)MM * EE,
                                     ctx, owb, ob, out);
}